// Round 1
// baseline (143.327 us; speedup 1.0000x reference)
//
#include <hip/hip_runtime.h>
#include <math.h>

// Problem constants
#define DD 256
#define HH 8
#define AA 32
#define SS 512
#define BB 2
constexpr float BCONST      = 0.9f;
constexpr float ONE_MINUS_B = 0.1f;      // fp32 of (1.0 - 0.9)
constexpr float EPSF        = 1e-10f;
constexpr float SCALEF      = 0.0625f;   // 1/sqrt(256), exact power of 2
constexpr float FLTMAX      = 3.402823466e38f;

// Workspace layout (float offsets)
//  qkv   [1024][768]   (q | k | v per row)
//  vp    [1024][256]   expm1(p * log(v_norm))
//  ew    [1024][256]   attention output (pre out-proj)
//  pmin  [16][256], pmax[16][256]  partial min/max over s-chunks
//  vminw [2][256], vrangew[2][256]
//  pw    [256]
#define OFF_QKV    0
#define OFF_VP     786432
#define OFF_EW     1048576
#define OFF_PMIN   1310720
#define OFF_PMAX   1314816
#define OFF_VMIN   1318912
#define OFF_VRANGE 1319424
#define OFF_P      1319936

// ---------------------------------------------------------------------------
// Generic row-by-row GEMM: C[i][j] = dot(A[i,:K], Brow(j)),
// Brow(j) = j < nsplit ? B0 + j*K : B1 + (j-nsplit)*K.
// 64x64 block tile, 4x4 micro-tile, BK=32, fp32.
// ---------------------------------------------------------------------------
__global__ __launch_bounds__(256) void gemm64(
    const float* __restrict__ A, const float* __restrict__ B0,
    const float* __restrict__ B1, int nsplit,
    float* __restrict__ C, int ldc, int K, int lda) {
  __shared__ float As[64][36];  // pad 36: fp32x4 aligned, stride%32=4
  __shared__ float Bs[64][36];
  const int i0 = blockIdx.x * 64;
  const int j0 = blockIdx.y * 64;
  const float* Bsrc = (j0 < nsplit) ? (B0 + (size_t)j0 * K)
                                    : (B1 + (size_t)(j0 - nsplit) * K);
  const int t  = threadIdx.x;
  const int lr = t >> 3;            // 0..31
  const int lc = (t & 7) << 2;      // 0,4,...,28
  const int tx = t & 15, ty = t >> 4;
  float acc[4][4] = {};
  for (int k0 = 0; k0 < K; k0 += 32) {
    float4 a0 = *(const float4*)(A + (size_t)(i0 + lr) * lda + k0 + lc);
    float4 a1 = *(const float4*)(A + (size_t)(i0 + lr + 32) * lda + k0 + lc);
    float4 b0 = *(const float4*)(Bsrc + (size_t)lr * K + k0 + lc);
    float4 b1 = *(const float4*)(Bsrc + (size_t)(lr + 32) * K + k0 + lc);
    __syncthreads();              // previous iteration's reads complete
    *(float4*)&As[lr][lc]      = a0;
    *(float4*)&As[lr + 32][lc] = a1;
    *(float4*)&Bs[lr][lc]      = b0;
    *(float4*)&Bs[lr + 32][lc] = b1;
    __syncthreads();
#pragma unroll
    for (int kk = 0; kk < 32; kk += 4) {
      float4 af[4], bf[4];
#pragma unroll
      for (int r = 0; r < 4; ++r) af[r] = *(const float4*)&As[ty * 4 + r][kk];
#pragma unroll
      for (int c = 0; c < 4; ++c) bf[c] = *(const float4*)&Bs[tx * 4 + c][kk];
#pragma unroll
      for (int r = 0; r < 4; ++r)
#pragma unroll
        for (int c = 0; c < 4; ++c)
          acc[r][c] += af[r].x * bf[c].x + af[r].y * bf[c].y +
                       af[r].z * bf[c].z + af[r].w * bf[c].w;
    }
  }
#pragma unroll
  for (int r = 0; r < 4; ++r) {
    float4 v4 = make_float4(acc[r][0], acc[r][1], acc[r][2], acc[r][3]);
    *(float4*)(C + (size_t)(i0 + ty * 4 + r) * ldc + j0 + tx * 4) = v4;
  }
}

// ---------------------------------------------------------------------------
// Partial min/max of v over s-chunks; block 0 also computes p vector.
// grid = B*8 blocks of 256 threads (one thread per d).
// ---------------------------------------------------------------------------
__global__ __launch_bounds__(256) void minmax_k(
    const float* __restrict__ qkv, const float* __restrict__ p_param,
    float* __restrict__ pmin, float* __restrict__ pmax, float* __restrict__ pw) {
  const int blk = blockIdx.x;          // 0..15
  const int b = blk >> 3, c = blk & 7;
  const int d = threadIdx.x;
  float mn = FLTMAX, mx = -FLTMAX;
  for (int s = c * 64; s < c * 64 + 64; ++s) {
    float v = qkv[((size_t)(b * 512 + s)) * 768 + 512 + d];
    mn = fminf(mn, v);
    mx = fmaxf(mx, v);
  }
  pmin[blk * 256 + d] = mn;
  pmax[blk * 256 + d] = mx;
  if (blk == 0) {
    float p = 50000.0f * tanhf(0.005f * p_param[d]) + 1.0f;
    if (p == 0.0f) p = 0.0001f;        // reference: p + (p==0)*P_MIN
    pw[d] = p;
  }
}

// ---------------------------------------------------------------------------
// vp = expm1(p * log(v_norm)); also materializes vmin / vrange per (b,d).
// grid = B*S blocks of 256 threads.
// ---------------------------------------------------------------------------
__global__ __launch_bounds__(256) void vpk(
    const float* __restrict__ qkv, const float* __restrict__ pmin,
    const float* __restrict__ pmax, const float* __restrict__ pw,
    float* __restrict__ vp, float* __restrict__ vminw, float* __restrict__ vrangew) {
  const int blk = blockIdx.x;           // 0..1023
  const int b = blk >> 9, s = blk & 511;
  const int d = threadIdx.x;
  float mn = pmin[(b * 8) * 256 + d];
  float mx = pmax[(b * 8) * 256 + d];
#pragma unroll
  for (int c = 1; c < 8; ++c) {
    mn = fminf(mn, pmin[(b * 8 + c) * 256 + d]);
    mx = fmaxf(mx, pmax[(b * 8 + c) * 256 + d]);
  }
  const float range = mx - mn + EPSF;
  const float v  = qkv[((size_t)(b * 512 + s)) * 768 + 512 + d];
  const float vn = (ONE_MINUS_B * (v - mn)) / range + BCONST;
  const float z  = pw[d] * logf(vn);
  vp[(size_t)blk * 256 + d] = expm1f(z);   // same sign for all k at fixed d
  if (s == 0) { vminw[b * 256 + d] = mn; vrangew[b * 256 + d] = range; }
}

// ---------------------------------------------------------------------------
// Fused attention: scores -> softmax -> SM @ VP -> robust power-mean epilogue.
// grid = (B*H, S/16); 256 threads; 16 queries per block.
// ---------------------------------------------------------------------------
__global__ __launch_bounds__(256) void attn_k(
    const float* __restrict__ qkv, const float* __restrict__ vp,
    const float* __restrict__ pw, const float* __restrict__ vminw,
    const float* __restrict__ vrangew, float* __restrict__ ew) {
  __shared__ float qs[16][36];     // q tile (pre-scaled by 1/16)
  __shared__ float sc[16][516];    // scores -> softmax weights
  __shared__ float kb[256][36];    // k / vp chunk buffer (reused as reduction)
  __shared__ float red[16][17];    // softmax row reductions
  const int bh  = blockIdx.x;
  const int b   = bh >> 3, h = bh & 7;
  const int q0g = blockIdx.y * 16;
  const int t   = threadIdx.x;

  if (t < 128) {                   // load q tile, fold in SCALE (exact *2^-4)
    const int q = t >> 3, c4 = (t & 7) << 2;
    float4 qv = *(const float4*)(qkv + ((size_t)(b * 512 + q0g + q)) * 768 + h * 32 + c4);
    qv.x *= SCALEF; qv.y *= SCALEF; qv.z *= SCALEF; qv.w *= SCALEF;
    *(float4*)&qs[q][c4] = qv;
  }

  // ---- Phase 1: scores (16 x 512), 2 chunks of 256 k; 4q x 4k micro-tile
  const int qg = t & 3;            // q0 = qg*4
  const int kg = t >> 2;           // 0..63, k0 = kg*4
  const int ldr = t >> 3, ldc4 = (t & 7) << 2;
  for (int kc = 0; kc < 2; ++kc) {
    __syncthreads();
#pragma unroll
    for (int rr = 0; rr < 256; rr += 32)
      *(float4*)&kb[ldr + rr][ldc4] = *(const float4*)(
          qkv + ((size_t)(b * 512 + kc * 256 + ldr + rr)) * 768 + 256 + h * 32 + ldc4);
    __syncthreads();
    float a2[4][4] = {};
#pragma unroll
    for (int kk = 0; kk < 32; kk += 4) {
      float4 qf[4], kf[4];
#pragma unroll
      for (int r = 0; r < 4; ++r) qf[r] = *(const float4*)&qs[qg * 4 + r][kk];
#pragma unroll
      for (int c = 0; c < 4; ++c) kf[c] = *(const float4*)&kb[kg * 4 + c][kk];
#pragma unroll
      for (int r = 0; r < 4; ++r)
#pragma unroll
        for (int c = 0; c < 4; ++c)
          a2[r][c] += qf[r].x * kf[c].x + qf[r].y * kf[c].y +
                      qf[r].z * kf[c].z + qf[r].w * kf[c].w;
    }
#pragma unroll
    for (int r = 0; r < 4; ++r)
      *(float4*)&sc[qg * 4 + r][kc * 256 + kg * 4] =
          make_float4(a2[r][0], a2[r][1], a2[r][2], a2[r][3]);
  }
  __syncthreads();

  // ---- Phase 2: softmax per row (16 threads per row, strided for banks)
  {
    const int q = t & 15, j = t >> 4;   // j: 0..15
    float m = -FLTMAX;
#pragma unroll
    for (int i = 0; i < 32; ++i) m = fmaxf(m, sc[q][j + 16 * i]);
    red[q][j] = m;
    __syncthreads();
    float rm = red[q][0];
#pragma unroll
    for (int jj = 1; jj < 16; ++jj) rm = fmaxf(rm, red[q][jj]);
    __syncthreads();                    // done reading maxes
    float ls = 0.f;
#pragma unroll
    for (int i = 0; i < 32; ++i) {
      float e = expf(sc[q][j + 16 * i] - rm);
      sc[q][j + 16 * i] = e;
      ls += e;
    }
    red[q][j] = ls;
    __syncthreads();
    float tot = 0.f;
#pragma unroll
    for (int jj = 0; jj < 16; ++jj) tot += red[q][jj];
    const float inv = 1.0f / tot;
#pragma unroll
    for (int i = 0; i < 32; ++i) sc[q][j + 16 * i] *= inv;
  }

  // ---- Phase 3: out[q][a] = sum_k sm[q][k] * vp[k][a]; 4q x 4a, k-split 8
  float a3[4][4] = {};
  const int qg3 = t & 3;            // q0 = qg3*4
  const int ag3 = (t >> 2) & 7;     // a0 = ag3*4
  const int ks  = t >> 5;           // 0..7 -> k-subrange ks*32..+31 per chunk
  for (int kc = 0; kc < 2; ++kc) {
    __syncthreads();
#pragma unroll
    for (int rr = 0; rr < 256; rr += 32)
      *(float4*)&kb[ldr + rr][ldc4] = *(const float4*)(
          vp + ((size_t)(b * 512 + kc * 256 + ldr + rr)) * 256 + h * 32 + ldc4);
    __syncthreads();
#pragma unroll
    for (int kk = 0; kk < 32; ++kk) {
      const int kl = ks * 32 + kk;
      const int kglob = kc * 256 + kl;
      const float4 vf = *(const float4*)&kb[kl][ag3 * 4];
      const float s0 = sc[qg3 * 4 + 0][kglob];
      const float s1 = sc[qg3 * 4 + 1][kglob];
      const float s2 = sc[qg3 * 4 + 2][kglob];
      const float s3 = sc[qg3 * 4 + 3][kglob];
      a3[0][0] += s0 * vf.x; a3[0][1] += s0 * vf.y; a3[0][2] += s0 * vf.z; a3[0][3] += s0 * vf.w;
      a3[1][0] += s1 * vf.x; a3[1][1] += s1 * vf.y; a3[1][2] += s1 * vf.z; a3[1][3] += s1 * vf.w;
      a3[2][0] += s2 * vf.x; a3[2][1] += s2 * vf.y; a3[2][2] += s2 * vf.z; a3[2][3] += s2 * vf.w;
      a3[3][0] += s3 * vf.x; a3[3][1] += s3 * vf.y; a3[3][2] += s3 * vf.z; a3[3][3] += s3 * vf.w;
    }
  }

  // ---- k-split reduction through LDS (reuse kb), then robust epilogue
  __syncthreads();
  float* part = &kb[0][0];          // [q16][a32][ks8] = 4096 floats
#pragma unroll
  for (int r = 0; r < 4; ++r)
#pragma unroll
    for (int c = 0; c < 4; ++c)
      part[(((qg3 * 4 + r) * 32) + ag3 * 4 + c) * 8 + ks] = a3[r][c];
  __syncthreads();
  {
    const int idx = t * 2;
    const int q = idx >> 5, a = idx & 31;   // two consecutive a per thread
    float o2[2];
#pragma unroll
    for (int o = 0; o < 2; ++o) {
      const float* p8 = part + ((size_t)(q * 32 + a + o)) * 8;
      float s = 0.f;
#pragma unroll
      for (int i = 0; i < 8; ++i) s += p8[i];
      const int d = h * 32 + a + o;
      const float p = pw[d];
      const float mean = log1pf(s);         // log(sum sm * v^p), robust near 1
      const float en = expf(mean / p);      // robust as p -> 0
      o2[o] = (en - BCONST) * vrangew[b * 256 + d] / ONE_MINUS_B + vminw[b * 256 + d];
    }
    *(float2*)(ew + ((size_t)(b * 512 + q0g + q)) * 256 + h * 32 + a) =
        make_float2(o2[0], o2[1]);
  }
}

// ---------------------------------------------------------------------------
extern "C" void kernel_launch(void* const* d_in, const int* in_sizes, int n_in,
                              void* d_out, int out_size, void* d_ws, size_t ws_size,
                              hipStream_t stream) {
  const float* ctx  = (const float*)d_in[0];
  const float* WQ   = (const float*)d_in[1];
  const float* WKV  = (const float*)d_in[2];
  const float* WOUT = (const float*)d_in[3];
  const float* PP   = (const float*)d_in[4];
  float* ws      = (float*)d_ws;
  float* qkv     = ws + OFF_QKV;
  float* vp      = ws + OFF_VP;
  float* ew      = ws + OFF_EW;
  float* pmin    = ws + OFF_PMIN;
  float* pmax    = ws + OFF_PMAX;
  float* vminw   = ws + OFF_VMIN;
  float* vrangew = ws + OFF_VRANGE;
  float* pw      = ws + OFF_P;
  float* out     = (float*)d_out;

  // Fused Q|K|V projection: C[i][j] = dot(context[i], W_Q/W_KV row)
  gemm64<<<dim3(16, 12), 256, 0, stream>>>(ctx, WQ, WKV, 256, qkv, 768, 256, 256);
  // Per-column v min/max partials + p vector
  minmax_k<<<16, 256, 0, stream>>>(qkv, PP, pmin, pmax, pw);
  // expm1(p * log(v_norm))
  vpk<<<1024, 256, 0, stream>>>(qkv, pmin, pmax, pw, vp, vminw, vrangew);
  // Fused attention + power-mean epilogue
  attn_k<<<dim3(16, 32), 256, 0, stream>>>(qkv, vp, pw, vminw, vrangew, ew);
  // Output projection
  gemm64<<<dim3(16, 4), 256, 0, stream>>>(ew, WOUT, WOUT, 256, out, 256, 256, 256);
}

// Round 3
// 130.072 us; speedup vs baseline: 1.1019x; 1.1019x over previous
//
#include <hip/hip_runtime.h>
#include <math.h>

// Problem constants
#define DD 256
#define HH 8
#define AA 32
#define SS 512
#define BB 2
constexpr float BCONST      = 0.9f;
constexpr float ONE_MINUS_B = 0.1f;
constexpr float EPSF        = 1e-10f;
constexpr float SCALEF      = 0.0625f;   // 1/sqrt(256), exact power of 2
constexpr float FLTMAX      = 3.402823466e38f;

// Workspace layout (float offsets)
#define OFF_QKV    0
#define OFF_VP     786432
#define OFF_EW     1048576
#define OFF_PMIN   1310720
#define OFF_PMAX   1314816
#define OFF_VMIN   1318912
#define OFF_VRANGE 1319424
#define OFF_P      1319936

// ---------------------------------------------------------------------------
// Tiled fp32 GEMM: C[i][j] = dot(A[i,:K], Brow(j)),
// Brow(j) = j < nsplit ? B0 + j*K : B1 + (j-nsplit)*K.
// Block tile TM x TN, micro-tile RM x RN, BK=32, 256 threads.
// Micro-tile columns are STRIDED (tx + CG*c): B-fragment ds_read_b128
// addresses spread over 8 bank-quads (2-way aliasing = free).
// Staging loads prefetched one K-step ahead into registers.
// ---------------------------------------------------------------------------
template<int TM, int TN, int RM, int RN>
__global__ __launch_bounds__(256) void gemm_t(
    const float* __restrict__ A, const float* __restrict__ B0,
    const float* __restrict__ B1, int nsplit,
    float* __restrict__ C, int ldc, int K, int lda) {
  constexpr int LDT = 36;              // LDS row stride (floats)
  constexpr int CG  = TN / RN;         // col groups (16)
  constexpr int NA  = TM * 32 / 1024;  // float4 staged per thread for A
  constexpr int NB  = TN * 32 / 1024;
  __shared__ float As[TM][LDT];
  __shared__ float Bs[TN][LDT];
  const int i0 = blockIdx.x * TM;
  const int j0 = blockIdx.y * TN;
  const float* Bsrc = (j0 < nsplit) ? (B0 + (size_t)j0 * K)
                                    : (B1 + (size_t)(j0 - nsplit) * K);
  const int t  = threadIdx.x;
  const int lr = t >> 3;               // staging row 0..31
  const int lc = (t & 7) << 2;         // staging col 0..28
  const int tx = t % CG, ty = t / CG;

  float4 pa[NA], pb[NB];
#pragma unroll
  for (int u = 0; u < NA; ++u)
    pa[u] = *(const float4*)(A + (size_t)(i0 + lr + 32 * u) * lda + lc);
#pragma unroll
  for (int u = 0; u < NB; ++u)
    pb[u] = *(const float4*)(Bsrc + (size_t)(lr + 32 * u) * K + lc);

  float acc[RM][RN] = {};
  for (int k0 = 0; k0 < K; k0 += 32) {
    __syncthreads();                   // previous iteration's LDS reads done
#pragma unroll
    for (int u = 0; u < NA; ++u) *(float4*)&As[lr + 32 * u][lc] = pa[u];
#pragma unroll
    for (int u = 0; u < NB; ++u) *(float4*)&Bs[lr + 32 * u][lc] = pb[u];
    __syncthreads();
    if (k0 + 32 < K) {                 // prefetch next K-step
#pragma unroll
      for (int u = 0; u < NA; ++u)
        pa[u] = *(const float4*)(A + (size_t)(i0 + lr + 32 * u) * lda + k0 + 32 + lc);
#pragma unroll
      for (int u = 0; u < NB; ++u)
        pb[u] = *(const float4*)(Bsrc + (size_t)(lr + 32 * u) * K + k0 + 32 + lc);
    }
#pragma unroll
    for (int kk = 0; kk < 32; kk += 4) {
      float4 af[RM], bf[RN];
#pragma unroll
      for (int r = 0; r < RM; ++r) af[r] = *(const float4*)&As[ty * RM + r][kk];
#pragma unroll
      for (int c = 0; c < RN; ++c) bf[c] = *(const float4*)&Bs[tx + CG * c][kk];
#pragma unroll
      for (int r = 0; r < RM; ++r)
#pragma unroll
        for (int c = 0; c < RN; ++c)
          acc[r][c] += af[r].x * bf[c].x + af[r].y * bf[c].y +
                       af[r].z * bf[c].z + af[r].w * bf[c].w;
    }
  }
#pragma unroll
  for (int r = 0; r < RM; ++r)
#pragma unroll
    for (int c = 0; c < RN; ++c)
      C[(size_t)(i0 + ty * RM + r) * ldc + j0 + tx + CG * c] = acc[r][c];
}

// ---------------------------------------------------------------------------
// Partial min/max of v over s-chunks; block 0 also computes p vector.
// ---------------------------------------------------------------------------
__global__ __launch_bounds__(256) void minmax_k(
    const float* __restrict__ qkv, const float* __restrict__ p_param,
    float* __restrict__ pmin, float* __restrict__ pmax, float* __restrict__ pw) {
  const int blk = blockIdx.x;          // 0..15
  const int b = blk >> 3, c = blk & 7;
  const int d = threadIdx.x;
  float mn = FLTMAX, mx = -FLTMAX;
  for (int s = c * 64; s < c * 64 + 64; ++s) {
    float v = qkv[((size_t)(b * 512 + s)) * 768 + 512 + d];
    mn = fminf(mn, v);
    mx = fmaxf(mx, v);
  }
  pmin[blk * 256 + d] = mn;
  pmax[blk * 256 + d] = mx;
  if (blk == 0) {
    float p = 50000.0f * tanhf(0.005f * p_param[d]) + 1.0f;
    if (p == 0.0f) p = 0.0001f;
    pw[d] = p;
  }
}

// ---------------------------------------------------------------------------
// vp = expm1(p * log(v_norm)); also materializes vmin / vrange per (b,d).
// ---------------------------------------------------------------------------
__global__ __launch_bounds__(256) void vpk(
    const float* __restrict__ qkv, const float* __restrict__ pmin,
    const float* __restrict__ pmax, const float* __restrict__ pw,
    float* __restrict__ vp, float* __restrict__ vminw, float* __restrict__ vrangew) {
  const int blk = blockIdx.x;           // 0..1023
  const int b = blk >> 9, s = blk & 511;
  const int d = threadIdx.x;
  float mn = pmin[(b * 8) * 256 + d];
  float mx = pmax[(b * 8) * 256 + d];
#pragma unroll
  for (int c = 1; c < 8; ++c) {
    mn = fminf(mn, pmin[(b * 8 + c) * 256 + d]);
    mx = fmaxf(mx, pmax[(b * 8 + c) * 256 + d]);
  }
  const float range = mx - mn + EPSF;
  const float v  = qkv[((size_t)(b * 512 + s)) * 768 + 512 + d];
  const float vn = (ONE_MINUS_B * (v - mn)) / range + BCONST;
  const float z  = pw[d] * logf(vn);
  vp[(size_t)blk * 256 + d] = expm1f(z);
  if (s == 0) { vminw[b * 256 + d] = mn; vrangew[b * 256 + d] = range; }
}

// ---------------------------------------------------------------------------
// Fused attention: scores -> softmax -> SM @ VP -> robust power-mean epilogue.
// grid = (B*H, S/16); 256 threads; 16 queries per block.
// Register-prefetched chunk staging; strided k-columns in phase 1;
// LDS-based (cross-wave correct!) k-split reduction in the epilogue.
// ---------------------------------------------------------------------------
__global__ __launch_bounds__(256) void attn_k(
    const float* __restrict__ qkv, const float* __restrict__ vp,
    const float* __restrict__ pw, const float* __restrict__ vminw,
    const float* __restrict__ vrangew, float* __restrict__ ew) {
  __shared__ float qs[16][36];
  __shared__ float sc[16][516];
  __shared__ float kb[256][36];
  __shared__ float red[16][17];
  const int bh  = blockIdx.x;
  const int b   = bh >> 3, h = bh & 7;
  const int q0g = blockIdx.y * 16;
  const int t   = threadIdx.x;
  const int ldr = t >> 3, ldc4 = (t & 7) << 2;

  if (t < 128) {                       // q tile, fold in SCALE (exact *2^-4)
    const int q = t >> 3, c4 = (t & 7) << 2;
    float4 qv = *(const float4*)(qkv + ((size_t)(b * 512 + q0g + q)) * 768 + h * 32 + c4);
    qv.x *= SCALEF; qv.y *= SCALEF; qv.z *= SCALEF; qv.w *= SCALEF;
    *(float4*)&qs[q][c4] = qv;
  }

  // prefetch K chunk 0
  float4 pk[8];
#pragma unroll
  for (int u = 0; u < 8; ++u)
    pk[u] = *(const float4*)(qkv + ((size_t)(b * 512 + ldr + 32 * u)) * 768 + 256 + h * 32 + ldc4);

  // ---- Phase 1: scores (16 x 512); cols strided kg + 64*c
  const int qg = t & 3;                // q rows qg*4+r
  const int kg = t >> 2;               // 0..63
  for (int kc = 0; kc < 2; ++kc) {
    __syncthreads();
#pragma unroll
    for (int u = 0; u < 8; ++u) *(float4*)&kb[ldr + 32 * u][ldc4] = pk[u];
    __syncthreads();
    if (kc == 0) {                     // prefetch K chunk 1
#pragma unroll
      for (int u = 0; u < 8; ++u)
        pk[u] = *(const float4*)(qkv + ((size_t)(b * 512 + 256 + ldr + 32 * u)) * 768 + 256 + h * 32 + ldc4);
    } else {                           // prefetch VP chunk 0 (for phase 3)
#pragma unroll
      for (int u = 0; u < 8; ++u)
        pk[u] = *(const float4*)(vp + ((size_t)(b * 512 + ldr + 32 * u)) * 256 + h * 32 + ldc4);
    }
    float a2[4][4] = {};
#pragma unroll
    for (int kk = 0; kk < 32; kk += 4) {
      float4 qf[4], kf[4];
#pragma unroll
      for (int r = 0; r < 4; ++r) qf[r] = *(const float4*)&qs[qg * 4 + r][kk];
#pragma unroll
      for (int c = 0; c < 4; ++c) kf[c] = *(const float4*)&kb[kg + 64 * c][kk];
#pragma unroll
      for (int r = 0; r < 4; ++r)
#pragma unroll
        for (int c = 0; c < 4; ++c)
          a2[r][c] += qf[r].x * kf[c].x + qf[r].y * kf[c].y +
                      qf[r].z * kf[c].z + qf[r].w * kf[c].w;
    }
#pragma unroll
    for (int r = 0; r < 4; ++r)
#pragma unroll
      for (int c = 0; c < 4; ++c)
        sc[qg * 4 + r][kc * 256 + kg + 64 * c] = a2[r][c];
  }
  __syncthreads();

  // ---- Phase 2: softmax per row (16 threads per row)
  {
    const int q = t & 15, j = t >> 4;
    float m = -FLTMAX;
#pragma unroll
    for (int i = 0; i < 32; ++i) m = fmaxf(m, sc[q][j + 16 * i]);
    red[q][j] = m;
    __syncthreads();
    float rm = red[q][0];
#pragma unroll
    for (int jj = 1; jj < 16; ++jj) rm = fmaxf(rm, red[q][jj]);
    __syncthreads();
    float ls = 0.f;
#pragma unroll
    for (int i = 0; i < 32; ++i) {
      float e = __expf(sc[q][j + 16 * i] - rm);
      sc[q][j + 16 * i] = e;
      ls += e;
    }
    red[q][j] = ls;
    __syncthreads();
    float tot = 0.f;
#pragma unroll
    for (int jj = 0; jj < 16; ++jj) tot += red[q][jj];
    const float inv = 1.0f / tot;
#pragma unroll
    for (int i = 0; i < 32; ++i) sc[q][j + 16 * i] *= inv;
  }

  // ---- Phase 3: out[q][a] = sum_k sm[q][k] * vp[k][a]; 4q x 4a, k-split 8
  float a3[4][4] = {};
  const int qg3 = t & 3;
  const int ag3 = (t >> 2) & 7;
  const int ks  = t >> 5;              // 0..7: slice ks spans ks*32..+31 per chunk
  for (int kc = 0; kc < 2; ++kc) {
    __syncthreads();
#pragma unroll
    for (int u = 0; u < 8; ++u) *(float4*)&kb[ldr + 32 * u][ldc4] = pk[u];
    __syncthreads();
    if (kc == 0) {                     // prefetch VP chunk 1
#pragma unroll
      for (int u = 0; u < 8; ++u)
        pk[u] = *(const float4*)(vp + ((size_t)(b * 512 + 256 + ldr + 32 * u)) * 256 + h * 32 + ldc4);
    }
#pragma unroll
    for (int kk = 0; kk < 32; ++kk) {
      const int kl = ks * 32 + kk;
      const int kglob = kc * 256 + kl;
      const float4 vf = *(const float4*)&kb[kl][ag3 * 4];
      const float s0 = sc[qg3 * 4 + 0][kglob];
      const float s1 = sc[qg3 * 4 + 1][kglob];
      const float s2 = sc[qg3 * 4 + 2][kglob];
      const float s3 = sc[qg3 * 4 + 3][kglob];
      a3[0][0] += s0 * vf.x; a3[0][1] += s0 * vf.y; a3[0][2] += s0 * vf.z; a3[0][3] += s0 * vf.w;
      a3[1][0] += s1 * vf.x; a3[1][1] += s1 * vf.y; a3[1][2] += s1 * vf.z; a3[1][3] += s1 * vf.w;
      a3[2][0] += s2 * vf.x; a3[2][1] += s2 * vf.y; a3[2][2] += s2 * vf.z; a3[2][3] += s2 * vf.w;
      a3[3][0] += s3 * vf.x; a3[3][1] += s3 * vf.y; a3[3][2] += s3 * vf.z; a3[3][3] += s3 * vf.w;
    }
  }

  // ---- k-split (8-way, spans ALL 4 waves) reduction through LDS, then
  // robust epilogue. NOTE: shfl cannot reduce this — slices live in
  // different waves (wave w holds ks = 2w, 2w+1). LDS is required.
  __syncthreads();
  float* part = &kb[0][0];             // [q16][a32][ks8] = 4096 floats
#pragma unroll
  for (int r = 0; r < 4; ++r)
#pragma unroll
    for (int c = 0; c < 4; ++c)
      part[(((qg3 * 4 + r) * 32) + ag3 * 4 + c) * 8 + ks] = a3[r][c];
  __syncthreads();
  {
    const int idx = t * 2;
    const int q = idx >> 5, a = idx & 31;   // two consecutive a per thread
    float o2[2];
#pragma unroll
    for (int o = 0; o < 2; ++o) {
      const float* p8 = part + ((size_t)(q * 32 + a + o)) * 8;
      float s = 0.f;
#pragma unroll
      for (int i = 0; i < 8; ++i) s += p8[i];
      const int d = h * 32 + a + o;
      const float p = pw[d];
      const float mean = log1pf(s);         // log(sum sm * v^p), robust near 1
      const float en = expf(mean / p);      // robust as p -> 0
      o2[o] = (en - BCONST) * vrangew[b * 256 + d] / ONE_MINUS_B + vminw[b * 256 + d];
    }
    *(float2*)(ew + ((size_t)(b * 512 + q0g + q)) * 256 + h * 32 + a) =
        make_float2(o2[0], o2[1]);
  }
}

// ---------------------------------------------------------------------------
extern "C" void kernel_launch(void* const* d_in, const int* in_sizes, int n_in,
                              void* d_out, int out_size, void* d_ws, size_t ws_size,
                              hipStream_t stream) {
  const float* ctx  = (const float*)d_in[0];
  const float* WQ   = (const float*)d_in[1];
  const float* WKV  = (const float*)d_in[2];
  const float* WOUT = (const float*)d_in[3];
  const float* PP   = (const float*)d_in[4];
  float* ws      = (float*)d_ws;
  float* qkv     = ws + OFF_QKV;
  float* vp      = ws + OFF_VP;
  float* ew      = ws + OFF_EW;
  float* pmin    = ws + OFF_PMIN;
  float* pmax    = ws + OFF_PMAX;
  float* vminw   = ws + OFF_VMIN;
  float* vrangew = ws + OFF_VRANGE;
  float* pw      = ws + OFF_P;
  float* out     = (float*)d_out;

  // Fused Q|K|V projection: 1024x768x256, 32x64 tiles -> 384 blocks
  gemm_t<32, 64, 2, 4><<<dim3(32, 12), 256, 0, stream>>>(
      ctx, WQ, WKV, 256, qkv, 768, 256, 256);
  // Per-column v min/max partials + p vector
  minmax_k<<<16, 256, 0, stream>>>(qkv, PP, pmin, pmax, pw);
  // expm1(p * log(v_norm))
  vpk<<<1024, 256, 0, stream>>>(qkv, pmin, pmax, pw, vp, vminw, vrangew);
  // Fused attention + power-mean epilogue
  attn_k<<<dim3(16, 32), 256, 0, stream>>>(qkv, vp, pw, vminw, vrangew, ew);
  // Output projection: 1024x256x256, 32x32 tiles -> 256 blocks
  gemm_t<32, 32, 2, 2><<<dim3(32, 8), 256, 0, stream>>>(
      ew, WOUT, WOUT, 1 << 30, out, 256, 256, 256);
}

// Round 4
// 123.381 us; speedup vs baseline: 1.1617x; 1.0542x over previous
//
#include <hip/hip_runtime.h>
#include <math.h>

// Problem constants
#define DD 256
#define HH 8
#define AA 32
#define SS 512
#define BB 2
constexpr float BCONST      = 0.9f;
constexpr float ONE_MINUS_B = 0.1f;
constexpr float EPSF        = 1e-10f;
constexpr float SCALEF      = 0.0625f;   // 1/sqrt(256), exact power of 2
constexpr float FLTMAX      = 3.402823466e38f;

// Workspace layout (float offsets)
#define OFF_QKV    0
#define OFF_VP     786432
#define OFF_EW     1048576
#define OFF_PMIN   1310720
#define OFF_PMAX   1318912
#define OFF_VMIN   1327104
#define OFF_VRANGE 1327616
#define OFF_P      1328128

// ---------------------------------------------------------------------------
// Tiled fp32 GEMM: C[i][j] = dot(A[i,:K], Brow(j)),
// Brow(j) = j < nsplit ? B0 + j*K : B1 + (j-nsplit)*K.
// Block tile TM x TN, micro-tile RM x RN, BK=32, 256 threads.
// Strided micro-tile columns (tx + CG*c): bank-conflict-free B fragments.
// Register prefetch one K-step ahead.
// MM=true (QKV only): blocks with j0>=512 own V columns; they reduce their
// 32-row tile's per-column min/max through LDS and write partials
// pminP/pmaxP[bx][d] (bx = row-tile 0..31), removing the minmax kernel.
// ---------------------------------------------------------------------------
template<int TM, int TN, int RM, int RN, bool MM>
__global__ __launch_bounds__(256) void gemm_t(
    const float* __restrict__ A, const float* __restrict__ B0,
    const float* __restrict__ B1, int nsplit,
    float* __restrict__ C, int ldc, int K, int lda,
    float* __restrict__ pminP, float* __restrict__ pmaxP) {
  constexpr int LDT = 36;              // LDS row stride (floats)
  constexpr int CG  = TN / RN;         // col groups (16)
  constexpr int NA  = TM * 32 / 1024;  // float4 staged per thread for A
  constexpr int NB  = TN * 32 / 1024;
  __shared__ float As[TM][LDT];
  __shared__ float Bs[TN][LDT];
  const int i0 = blockIdx.x * TM;
  const int j0 = blockIdx.y * TN;
  const float* Bsrc = (j0 < nsplit) ? (B0 + (size_t)j0 * K)
                                    : (B1 + (size_t)(j0 - nsplit) * K);
  const int t  = threadIdx.x;
  const int lr = t >> 3;               // staging row 0..31
  const int lc = (t & 7) << 2;         // staging col 0..28
  const int tx = t % CG, ty = t / CG;

  float4 pa[NA], pb[NB];
#pragma unroll
  for (int u = 0; u < NA; ++u)
    pa[u] = *(const float4*)(A + (size_t)(i0 + lr + 32 * u) * lda + lc);
#pragma unroll
  for (int u = 0; u < NB; ++u)
    pb[u] = *(const float4*)(Bsrc + (size_t)(lr + 32 * u) * K + lc);

  float acc[RM][RN] = {};
  for (int k0 = 0; k0 < K; k0 += 32) {
    __syncthreads();                   // previous iteration's LDS reads done
#pragma unroll
    for (int u = 0; u < NA; ++u) *(float4*)&As[lr + 32 * u][lc] = pa[u];
#pragma unroll
    for (int u = 0; u < NB; ++u) *(float4*)&Bs[lr + 32 * u][lc] = pb[u];
    __syncthreads();
    if (k0 + 32 < K) {                 // prefetch next K-step
#pragma unroll
      for (int u = 0; u < NA; ++u)
        pa[u] = *(const float4*)(A + (size_t)(i0 + lr + 32 * u) * lda + k0 + 32 + lc);
#pragma unroll
      for (int u = 0; u < NB; ++u)
        pb[u] = *(const float4*)(Bsrc + (size_t)(lr + 32 * u) * K + k0 + 32 + lc);
    }
#pragma unroll
    for (int kk = 0; kk < 32; kk += 4) {
      float4 af[RM], bf[RN];
#pragma unroll
      for (int r = 0; r < RM; ++r) af[r] = *(const float4*)&As[ty * RM + r][kk];
#pragma unroll
      for (int c = 0; c < RN; ++c) bf[c] = *(const float4*)&Bs[tx + CG * c][kk];
#pragma unroll
      for (int r = 0; r < RM; ++r)
#pragma unroll
        for (int c = 0; c < RN; ++c)
          acc[r][c] += af[r].x * bf[c].x + af[r].y * bf[c].y +
                       af[r].z * bf[c].z + af[r].w * bf[c].w;
    }
  }
#pragma unroll
  for (int r = 0; r < RM; ++r)
#pragma unroll
    for (int c = 0; c < RN; ++c)
      C[(size_t)(i0 + ty * RM + r) * ldc + j0 + tx + CG * c] = acc[r][c];

  if (MM && j0 >= 512) {               // V-column min/max partials
    __syncthreads();                   // done with As/Bs main-loop reads
    float* mnb = &As[0][0];            // [64 cols][17] (1088 <= TM*LDT)
    float* mxb = &Bs[0][0];
#pragma unroll
    for (int c = 0; c < RN; ++c) {
      float mn = acc[0][c], mx = acc[0][c];
#pragma unroll
      for (int r = 1; r < RM; ++r) {
        mn = fminf(mn, acc[r][c]);
        mx = fmaxf(mx, acc[r][c]);
      }
      mnb[(tx + CG * c) * 17 + ty] = mn;
      mxb[(tx + CG * c) * 17 + ty] = mx;
    }
    __syncthreads();
    if (t < TN) {
      float mn = mnb[t * 17], mx = mxb[t * 17];
#pragma unroll
      for (int i = 1; i < 16; ++i) {
        mn = fminf(mn, mnb[t * 17 + i]);
        mx = fmaxf(mx, mxb[t * 17 + i]);
      }
      const int bx = i0 >> 5;          // row-tile 0..31
      pminP[bx * 256 + (j0 - 512) + t] = mn;
      pmaxP[bx * 256 + (j0 - 512) + t] = mx;
    }
  }
}

// ---------------------------------------------------------------------------
// vp = expm1(p * log(v_norm)); p computed locally (1 tanhf/thread);
// also materializes vmin / vrange per (b,d) and pw (block 0).
// ---------------------------------------------------------------------------
__global__ __launch_bounds__(256) void vpk(
    const float* __restrict__ qkv, const float* __restrict__ pminP,
    const float* __restrict__ pmaxP, const float* __restrict__ p_param,
    float* __restrict__ vp, float* __restrict__ vminw,
    float* __restrict__ vrangew, float* __restrict__ pw) {
  const int blk = blockIdx.x;           // 0..1023
  const int b = blk >> 9, s = blk & 511;
  const int d = threadIdx.x;
  float mn = pminP[(b * 16) * 256 + d];
  float mx = pmaxP[(b * 16) * 256 + d];
#pragma unroll
  for (int c = 1; c < 16; ++c) {
    mn = fminf(mn, pminP[(b * 16 + c) * 256 + d]);
    mx = fmaxf(mx, pmaxP[(b * 16 + c) * 256 + d]);
  }
  float p = 50000.0f * tanhf(0.005f * p_param[d]) + 1.0f;
  if (p == 0.0f) p = 0.0001f;
  const float range = mx - mn + EPSF;
  const float v  = qkv[((size_t)(b * 512 + s)) * 768 + 512 + d];
  const float vn = (ONE_MINUS_B * (v - mn)) / range + BCONST;
  const float z  = p * logf(vn);
  vp[(size_t)blk * 256 + d] = expm1f(z);
  if (s == 0) { vminw[b * 256 + d] = mn; vrangew[b * 256 + d] = range; }
  if (blk == 0) pw[d] = p;
}

// ---------------------------------------------------------------------------
// Fused attention: scores -> 2-pass softmax (unnormalized) -> SM @ VP ->
// normalize + robust power-mean epilogue.
// grid = (B*H, S/16); 256 threads; 16 queries per block.
// ---------------------------------------------------------------------------
__global__ __launch_bounds__(256) void attn_k(
    const float* __restrict__ qkv, const float* __restrict__ vp,
    const float* __restrict__ pw, const float* __restrict__ vminw,
    const float* __restrict__ vrangew, float* __restrict__ ew) {
  __shared__ float qs[16][36];
  __shared__ float sc[16][516];
  __shared__ float kb[256][36];
  __shared__ float red[16][17];       // [q][0..15]=partials, [q][16]=T
  const int bh  = blockIdx.x;
  const int b   = bh >> 3, h = bh & 7;
  const int q0g = blockIdx.y * 16;
  const int t   = threadIdx.x;
  const int ldr = t >> 3, ldc4 = (t & 7) << 2;

  if (t < 128) {                       // q tile, fold in SCALE (exact *2^-4)
    const int q = t >> 3, c4 = (t & 7) << 2;
    float4 qv = *(const float4*)(qkv + ((size_t)(b * 512 + q0g + q)) * 768 + h * 32 + c4);
    qv.x *= SCALEF; qv.y *= SCALEF; qv.z *= SCALEF; qv.w *= SCALEF;
    *(float4*)&qs[q][c4] = qv;
  }

  // prefetch K chunk 0
  float4 pk[8];
#pragma unroll
  for (int u = 0; u < 8; ++u)
    pk[u] = *(const float4*)(qkv + ((size_t)(b * 512 + ldr + 32 * u)) * 768 + 256 + h * 32 + ldc4);

  // ---- Phase 1: scores (16 x 512); cols strided kg + 64*c
  const int qg = t & 3;                // q rows qg*4+r
  const int kg = t >> 2;               // 0..63
  for (int kc = 0; kc < 2; ++kc) {
    __syncthreads();
#pragma unroll
    for (int u = 0; u < 8; ++u) *(float4*)&kb[ldr + 32 * u][ldc4] = pk[u];
    __syncthreads();
    if (kc == 0) {                     // prefetch K chunk 1
#pragma unroll
      for (int u = 0; u < 8; ++u)
        pk[u] = *(const float4*)(qkv + ((size_t)(b * 512 + 256 + ldr + 32 * u)) * 768 + 256 + h * 32 + ldc4);
    } else {                           // prefetch VP chunk 0 (for phase 3)
#pragma unroll
      for (int u = 0; u < 8; ++u)
        pk[u] = *(const float4*)(vp + ((size_t)(b * 512 + ldr + 32 * u)) * 256 + h * 32 + ldc4);
    }
    float a2[4][4] = {};
#pragma unroll
    for (int kk = 0; kk < 32; kk += 4) {
      float4 qf[4], kf[4];
#pragma unroll
      for (int r = 0; r < 4; ++r) qf[r] = *(const float4*)&qs[qg * 4 + r][kk];
#pragma unroll
      for (int c = 0; c < 4; ++c) kf[c] = *(const float4*)&kb[kg + 64 * c][kk];
#pragma unroll
      for (int r = 0; r < 4; ++r)
#pragma unroll
        for (int c = 0; c < 4; ++c)
          a2[r][c] += qf[r].x * kf[c].x + qf[r].y * kf[c].y +
                      qf[r].z * kf[c].z + qf[r].w * kf[c].w;
    }
#pragma unroll
    for (int r = 0; r < 4; ++r)
#pragma unroll
      for (int c = 0; c < 4; ++c)
        sc[qg * 4 + r][kc * 256 + kg + 64 * c] = a2[r][c];
  }
  __syncthreads();

  // ---- Phase 2: 2-pass softmax per row; sc keeps UNNORMALIZED e; T->red[q][16]
  {
    const int q = t & 15, j = t >> 4;
    float m = -FLTMAX;
#pragma unroll
    for (int i = 0; i < 32; ++i) m = fmaxf(m, sc[q][j + 16 * i]);
    red[q][j] = m;
    __syncthreads();
    float rm = red[q][0];
#pragma unroll
    for (int jj = 1; jj < 16; ++jj) rm = fmaxf(rm, red[q][jj]);
    __syncthreads();                   // all reads of maxes done
    float ls = 0.f;
#pragma unroll
    for (int i = 0; i < 32; ++i) {
      float e = __expf(sc[q][j + 16 * i] - rm);
      sc[q][j + 16 * i] = e;
      ls += e;
    }
    red[q][j] = ls;
    __syncthreads();
    if (j == 0) {                      // publish T once per row
      float tot = 0.f;
#pragma unroll
      for (int jj = 0; jj < 16; ++jj) tot += red[q][jj];
      red[q][16] = tot;
    }
  }

  // ---- Phase 3: ACC[q][a] = sum_k e[q][k] * vp[k][a]; 4q x 4a, k-split 8
  float a3[4][4] = {};
  const int qg3 = t & 3;
  const int ag3 = (t >> 2) & 7;
  const int ks  = t >> 5;              // 0..7: slice ks spans ks*32..+31 per chunk
  for (int kc = 0; kc < 2; ++kc) {
    __syncthreads();
#pragma unroll
    for (int u = 0; u < 8; ++u) *(float4*)&kb[ldr + 32 * u][ldc4] = pk[u];
    __syncthreads();
    if (kc == 0) {                     // prefetch VP chunk 1
#pragma unroll
      for (int u = 0; u < 8; ++u)
        pk[u] = *(const float4*)(vp + ((size_t)(b * 512 + 256 + ldr + 32 * u)) * 256 + h * 32 + ldc4);
    }
#pragma unroll
    for (int kk = 0; kk < 32; ++kk) {
      const int kl = ks * 32 + kk;
      const int kglob = kc * 256 + kl;
      const float4 vf = *(const float4*)&kb[kl][ag3 * 4];
      const float s0 = sc[qg3 * 4 + 0][kglob];
      const float s1 = sc[qg3 * 4 + 1][kglob];
      const float s2 = sc[qg3 * 4 + 2][kglob];
      const float s3 = sc[qg3 * 4 + 3][kglob];
      a3[0][0] += s0 * vf.x; a3[0][1] += s0 * vf.y; a3[0][2] += s0 * vf.z; a3[0][3] += s0 * vf.w;
      a3[1][0] += s1 * vf.x; a3[1][1] += s1 * vf.y; a3[1][2] += s1 * vf.z; a3[1][3] += s1 * vf.w;
      a3[2][0] += s2 * vf.x; a3[2][1] += s2 * vf.y; a3[2][2] += s2 * vf.z; a3[2][3] += s2 * vf.w;
      a3[3][0] += s3 * vf.x; a3[3][1] += s3 * vf.y; a3[3][2] += s3 * vf.z; a3[3][3] += s3 * vf.w;
    }
  }

  // ---- k-split (8-way, spans ALL 4 waves) reduction through LDS, then
  // normalize by T and robust epilogue. (shfl can't reduce across waves.)
  __syncthreads();
  float* part = &kb[0][0];             // [q16][a32][ks8] = 4096 floats
#pragma unroll
  for (int r = 0; r < 4; ++r)
#pragma unroll
    for (int c = 0; c < 4; ++c)
      part[(((qg3 * 4 + r) * 32) + ag3 * 4 + c) * 8 + ks] = a3[r][c];
  __syncthreads();
  {
    const int idx = t * 2;
    const int q = idx >> 5, a = idx & 31;   // two consecutive a per thread
    const float invT = 1.0f / red[q][16];
    float o2[2];
#pragma unroll
    for (int o = 0; o < 2; ++o) {
      const float* p8 = part + ((size_t)(q * 32 + a + o)) * 8;
      float s = 0.f;
#pragma unroll
      for (int i = 0; i < 8; ++i) s += p8[i];
      s *= invT;
      const int d = h * 32 + a + o;
      const float p = pw[d];
      const float mean = log1pf(s);         // log(sum sm * v^p), robust near 1
      const float en = expf(mean / p);      // robust as p -> 0
      o2[o] = (en - BCONST) * vrangew[b * 256 + d] / ONE_MINUS_B + vminw[b * 256 + d];
    }
    *(float2*)(ew + ((size_t)(b * 512 + q0g + q)) * 256 + h * 32 + a) =
        make_float2(o2[0], o2[1]);
  }
}

// ---------------------------------------------------------------------------
extern "C" void kernel_launch(void* const* d_in, const int* in_sizes, int n_in,
                              void* d_out, int out_size, void* d_ws, size_t ws_size,
                              hipStream_t stream) {
  const float* ctx  = (const float*)d_in[0];
  const float* WQ   = (const float*)d_in[1];
  const float* WKV  = (const float*)d_in[2];
  const float* WOUT = (const float*)d_in[3];
  const float* PP   = (const float*)d_in[4];
  float* ws      = (float*)d_ws;
  float* qkv     = ws + OFF_QKV;
  float* vp      = ws + OFF_VP;
  float* ew      = ws + OFF_EW;
  float* pminP   = ws + OFF_PMIN;
  float* pmaxP   = ws + OFF_PMAX;
  float* vminw   = ws + OFF_VMIN;
  float* vrangew = ws + OFF_VRANGE;
  float* pw      = ws + OFF_P;
  float* out     = (float*)d_out;

  // Fused Q|K|V projection + V min/max partials: 1024x768x256, 32x64 tiles
  gemm_t<32, 64, 2, 4, true><<<dim3(32, 12), 256, 0, stream>>>(
      ctx, WQ, WKV, 256, qkv, 768, 256, 256, pminP, pmaxP);
  // expm1(p * log(v_norm)) + p vector + vmin/vrange
  vpk<<<1024, 256, 0, stream>>>(qkv, pminP, pmaxP, PP, vp, vminw, vrangew, pw);
  // Fused attention + power-mean epilogue
  attn_k<<<dim3(16, 32), 256, 0, stream>>>(qkv, vp, pw, vminw, vrangew, ew);
  // Output projection: 1024x256x256, 32x32 tiles
  gemm_t<32, 32, 2, 2, false><<<dim3(32, 8), 256, 0, stream>>>(
      ew, WOUT, WOUT, 1 << 30, out, 256, 256, 256, nullptr, nullptr);
}

// Round 5
// 122.935 us; speedup vs baseline: 1.1659x; 1.0036x over previous
//
#include <hip/hip_runtime.h>
#include <math.h>

// Problem constants
#define DD 256
#define HH 8
#define AA 32
#define SS 512
#define BB 2
constexpr float BCONST      = 0.9f;
constexpr float ONE_MINUS_B = 0.1f;
constexpr float EPSF        = 1e-10f;
constexpr float SCALEF      = 0.0625f;   // 1/sqrt(256), exact power of 2
constexpr float FLTMAX      = 3.402823466e38f;

// Workspace layout (float offsets)
#define OFF_QKV    0
#define OFF_EW     786432
#define OFF_PMIN   1048576
#define OFF_PMAX   1056768

// ---------------------------------------------------------------------------
// Tiled fp32 GEMM: C[i][j] = dot(A[i,:K], Brow(j)),
// Brow(j) = j < nsplit ? B0 + j*K : B1 + (j-nsplit)*K.
// Block tile TM x TN, micro-tile RM x RN, BK=32, 256 threads.
// Strided micro-tile columns (tx + CG*c): bank-conflict-free B fragments.
// Register prefetch one K-step ahead.
// MM=true (QKV only): blocks with j0>=512 own V columns; they reduce their
// 32-row tile's per-column min/max through LDS and write partials
// pminP/pmaxP[bx][d] (bx = row-tile 0..31).
// ---------------------------------------------------------------------------
template<int TM, int TN, int RM, int RN, bool MM>
__global__ __launch_bounds__(256) void gemm_t(
    const float* __restrict__ A, const float* __restrict__ B0,
    const float* __restrict__ B1, int nsplit,
    float* __restrict__ C, int ldc, int K, int lda,
    float* __restrict__ pminP, float* __restrict__ pmaxP) {
  constexpr int LDT = 36;              // LDS row stride (floats)
  constexpr int CG  = TN / RN;         // col groups (16)
  constexpr int NA  = TM * 32 / 1024;  // float4 staged per thread for A
  constexpr int NB  = TN * 32 / 1024;
  __shared__ float As[TM][LDT];
  __shared__ float Bs[TN][LDT];
  const int i0 = blockIdx.x * TM;
  const int j0 = blockIdx.y * TN;
  const float* Bsrc = (j0 < nsplit) ? (B0 + (size_t)j0 * K)
                                    : (B1 + (size_t)(j0 - nsplit) * K);
  const int t  = threadIdx.x;
  const int lr = t >> 3;               // staging row 0..31
  const int lc = (t & 7) << 2;         // staging col 0..28
  const int tx = t % CG, ty = t / CG;

  float4 pa[NA], pb[NB];
#pragma unroll
  for (int u = 0; u < NA; ++u)
    pa[u] = *(const float4*)(A + (size_t)(i0 + lr + 32 * u) * lda + lc);
#pragma unroll
  for (int u = 0; u < NB; ++u)
    pb[u] = *(const float4*)(Bsrc + (size_t)(lr + 32 * u) * K + lc);

  float acc[RM][RN] = {};
  for (int k0 = 0; k0 < K; k0 += 32) {
    __syncthreads();                   // previous iteration's LDS reads done
#pragma unroll
    for (int u = 0; u < NA; ++u) *(float4*)&As[lr + 32 * u][lc] = pa[u];
#pragma unroll
    for (int u = 0; u < NB; ++u) *(float4*)&Bs[lr + 32 * u][lc] = pb[u];
    __syncthreads();
    if (k0 + 32 < K) {                 // prefetch next K-step
#pragma unroll
      for (int u = 0; u < NA; ++u)
        pa[u] = *(const float4*)(A + (size_t)(i0 + lr + 32 * u) * lda + k0 + 32 + lc);
#pragma unroll
      for (int u = 0; u < NB; ++u)
        pb[u] = *(const float4*)(Bsrc + (size_t)(lr + 32 * u) * K + k0 + 32 + lc);
    }
#pragma unroll
    for (int kk = 0; kk < 32; kk += 4) {
      float4 af[RM], bf[RN];
#pragma unroll
      for (int r = 0; r < RM; ++r) af[r] = *(const float4*)&As[ty * RM + r][kk];
#pragma unroll
      for (int c = 0; c < RN; ++c) bf[c] = *(const float4*)&Bs[tx + CG * c][kk];
#pragma unroll
      for (int r = 0; r < RM; ++r)
#pragma unroll
        for (int c = 0; c < RN; ++c)
          acc[r][c] += af[r].x * bf[c].x + af[r].y * bf[c].y +
                       af[r].z * bf[c].z + af[r].w * bf[c].w;
    }
  }
#pragma unroll
  for (int r = 0; r < RM; ++r)
#pragma unroll
    for (int c = 0; c < RN; ++c)
      C[(size_t)(i0 + ty * RM + r) * ldc + j0 + tx + CG * c] = acc[r][c];

  if (MM && j0 >= 512) {               // V-column min/max partials
    __syncthreads();                   // done with As/Bs main-loop reads
    float* mnb = &As[0][0];            // [64 cols][17]
    float* mxb = &Bs[0][0];
#pragma unroll
    for (int c = 0; c < RN; ++c) {
      float mn = acc[0][c], mx = acc[0][c];
#pragma unroll
      for (int r = 1; r < RM; ++r) {
        mn = fminf(mn, acc[r][c]);
        mx = fmaxf(mx, acc[r][c]);
      }
      mnb[(tx + CG * c) * 17 + ty] = mn;
      mxb[(tx + CG * c) * 17 + ty] = mx;
    }
    __syncthreads();
    if (t < TN) {
      float mn = mnb[t * 17], mx = mxb[t * 17];
#pragma unroll
      for (int i = 1; i < 16; ++i) {
        mn = fminf(mn, mnb[t * 17 + i]);
        mx = fmaxf(mx, mxb[t * 17 + i]);
      }
      const int bx = i0 >> 5;          // row-tile 0..31
      pminP[bx * 256 + (j0 - 512) + t] = mn;
      pmaxP[bx * 256 + (j0 - 512) + t] = mx;
    }
  }
}

// ---------------------------------------------------------------------------
// Fused attention: V-transform (fused vpk) + scores -> 2-pass softmax
// (unnormalized) -> SM @ VP -> normalize + robust power-mean epilogue.
// grid = (B*H, S/16); 256 threads; 16 queries per block.
// sc row stride 520: q-rows hit distinct bank-quads for b128 reads.
// Scores written/read as float4 (contiguous k per micro-tile column).
// ---------------------------------------------------------------------------
__global__ __launch_bounds__(256) void attn_k(
    const float* __restrict__ qkv, const float* __restrict__ pminP,
    const float* __restrict__ pmaxP, const float* __restrict__ p_param,
    float* __restrict__ ew) {
  __shared__ float qs[16][36];
  __shared__ float sc[16][520];        // scores (then unnormalized softmax e)
  __shared__ float kb[256][36];        // K / transformed-V chunk buffer
  __shared__ float red[16][17];        // [q][0..15]=partials, [q][16]=T
  __shared__ float pl_mn[32], pl_rg[32], pl_p[32];
  const int bh  = blockIdx.x;
  const int b   = bh >> 3, h = bh & 7;
  const int q0g = blockIdx.y * 16;
  const int t   = threadIdx.x;
  const int ldr = t >> 3, ldc4 = (t & 7) << 2;

  if (t < 128) {                       // q tile, fold in SCALE (exact *2^-4)
    const int q = t >> 3, c4 = (t & 7) << 2;
    float4 qv = *(const float4*)(qkv + ((size_t)(b * 512 + q0g + q)) * 768 + h * 32 + c4);
    qv.x *= SCALEF; qv.y *= SCALEF; qv.z *= SCALEF; qv.w *= SCALEF;
    *(float4*)&qs[q][c4] = qv;
  }
  if (t < 32) {                        // per-column mn/range/p (fused vpk)
    const int d = h * 32 + t;
    float mn = pminP[(b * 16) * 256 + d];
    float mx = pmaxP[(b * 16) * 256 + d];
#pragma unroll
    for (int c = 1; c < 16; ++c) {
      mn = fminf(mn, pminP[(b * 16 + c) * 256 + d]);
      mx = fmaxf(mx, pmaxP[(b * 16 + c) * 256 + d]);
    }
    float p = 50000.0f * tanhf(0.005f * p_param[d]) + 1.0f;
    if (p == 0.0f) p = 0.0001f;
    pl_mn[t] = mn;
    pl_rg[t] = mx - mn + EPSF;
    pl_p[t]  = p;
  }

  // prefetch K chunk 0
  float4 pk[8];
#pragma unroll
  for (int u = 0; u < 8; ++u)
    pk[u] = *(const float4*)(qkv + ((size_t)(b * 512 + ldr + 32 * u)) * 768 + 256 + h * 32 + ldc4);

  // ---- Phase 1: scores (16 x 512); k-cols CONTIGUOUS per thread (kg*4+c)
  const int qg = t & 3;                // q rows qg*4+r
  const int kg = t >> 2;               // 0..63 -> k-cols kg*4..+3
  for (int kc = 0; kc < 2; ++kc) {
    __syncthreads();
#pragma unroll
    for (int u = 0; u < 8; ++u) *(float4*)&kb[ldr + 32 * u][ldc4] = pk[u];
    __syncthreads();
    if (kc == 0) {                     // prefetch K chunk 1
#pragma unroll
      for (int u = 0; u < 8; ++u)
        pk[u] = *(const float4*)(qkv + ((size_t)(b * 512 + 256 + ldr + 32 * u)) * 768 + 256 + h * 32 + ldc4);
    } else {                           // prefetch RAW V chunk 0 (for phase 3)
#pragma unroll
      for (int u = 0; u < 8; ++u)
        pk[u] = *(const float4*)(qkv + ((size_t)(b * 512 + ldr + 32 * u)) * 768 + 512 + h * 32 + ldc4);
    }
    float a2[4][4] = {};
#pragma unroll
    for (int kk = 0; kk < 32; kk += 4) {
      float4 qf[4], kf[4];
#pragma unroll
      for (int r = 0; r < 4; ++r) qf[r] = *(const float4*)&qs[qg * 4 + r][kk];
#pragma unroll
      for (int c = 0; c < 4; ++c) kf[c] = *(const float4*)&kb[kg * 4 + c][kk];
#pragma unroll
      for (int r = 0; r < 4; ++r)
#pragma unroll
        for (int c = 0; c < 4; ++c)
          a2[r][c] += qf[r].x * kf[c].x + qf[r].y * kf[c].y +
                      qf[r].z * kf[c].z + qf[r].w * kf[c].w;
    }
#pragma unroll
    for (int r = 0; r < 4; ++r)
      *(float4*)&sc[qg * 4 + r][kc * 256 + kg * 4] =
          make_float4(a2[r][0], a2[r][1], a2[r][2], a2[r][3]);
  }
  __syncthreads();

  // ---- Phase 2: 2-pass softmax; thread (q,j) owns contiguous k in [32j,32j+32)
  {
    const int q = t & 15, j = t >> 4;
    float m = -FLTMAX;
#pragma unroll
    for (int g = 0; g < 8; ++g) {
      float4 x = *(const float4*)&sc[q][j * 32 + 4 * g];
      m = fmaxf(m, fmaxf(fmaxf(x.x, x.y), fmaxf(x.z, x.w)));
    }
    red[q][j] = m;
    __syncthreads();
    float rm = red[q][0];
#pragma unroll
    for (int jj = 1; jj < 16; ++jj) rm = fmaxf(rm, red[q][jj]);
    __syncthreads();                   // all reads of maxes done
    float ls = 0.f;
#pragma unroll
    for (int g = 0; g < 8; ++g) {
      float4 x = *(const float4*)&sc[q][j * 32 + 4 * g];
      x.x = __expf(x.x - rm); x.y = __expf(x.y - rm);
      x.z = __expf(x.z - rm); x.w = __expf(x.w - rm);
      *(float4*)&sc[q][j * 32 + 4 * g] = x;
      ls += x.x + x.y + x.z + x.w;
    }
    red[q][j] = ls;
    __syncthreads();
    if (j == 0) {                      // publish T once per row
      float tot = 0.f;
#pragma unroll
      for (int jj = 0; jj < 16; ++jj) tot += red[q][jj];
      red[q][16] = tot;
    }
  }

  // ---- Phase 3: ACC[q][a] = sum_k e[q][k]*vp[k][a]; 4q x 4a, k-split 8.
  // V transformed to expm1(p*log(vn)) at staging time (fused vpk).
  float a3[4][4] = {};
  const int qg3 = t & 3;
  const int ag3 = (t >> 2) & 7;
  const int ks  = t >> 5;              // 0..7: slice ks*32..+31 per chunk
  for (int kc = 0; kc < 2; ++kc) {
    __syncthreads();
#pragma unroll
    for (int u = 0; u < 8; ++u) {
      const float4 vv = pk[u];
      float4 tv;
      tv.x = expm1f(pl_p[ldc4 + 0] * logf((ONE_MINUS_B * (vv.x - pl_mn[ldc4 + 0])) / pl_rg[ldc4 + 0] + BCONST));
      tv.y = expm1f(pl_p[ldc4 + 1] * logf((ONE_MINUS_B * (vv.y - pl_mn[ldc4 + 1])) / pl_rg[ldc4 + 1] + BCONST));
      tv.z = expm1f(pl_p[ldc4 + 2] * logf((ONE_MINUS_B * (vv.z - pl_mn[ldc4 + 2])) / pl_rg[ldc4 + 2] + BCONST));
      tv.w = expm1f(pl_p[ldc4 + 3] * logf((ONE_MINUS_B * (vv.w - pl_mn[ldc4 + 3])) / pl_rg[ldc4 + 3] + BCONST));
      *(float4*)&kb[ldr + 32 * u][ldc4] = tv;
    }
    __syncthreads();
    if (kc == 0) {                     // prefetch RAW V chunk 1
#pragma unroll
      for (int u = 0; u < 8; ++u)
        pk[u] = *(const float4*)(qkv + ((size_t)(b * 512 + 256 + ldr + 32 * u)) * 768 + 512 + h * 32 + ldc4);
    }
#pragma unroll
    for (int g = 0; g < 8; ++g) {
      const int k0 = ks * 32 + g * 4;
      float4 s4[4], vf[4];
#pragma unroll
      for (int r = 0; r < 4; ++r)
        s4[r] = *(const float4*)&sc[qg3 * 4 + r][kc * 256 + k0];
#pragma unroll
      for (int c = 0; c < 4; ++c)
        vf[c] = *(const float4*)&kb[k0 + c][ag3 * 4];
#pragma unroll
      for (int r = 0; r < 4; ++r) {
        const float* sp = (const float*)&s4[r];
#pragma unroll
        for (int c = 0; c < 4; ++c) {
          const float sv = sp[c];
          a3[r][0] += sv * vf[c].x; a3[r][1] += sv * vf[c].y;
          a3[r][2] += sv * vf[c].z; a3[r][3] += sv * vf[c].w;
        }
      }
    }
  }

  // ---- k-split (8-way, spans ALL 4 waves) reduction through LDS, then
  // normalize by T and robust epilogue. (shfl can't reduce across waves.)
  __syncthreads();
  float* part = &kb[0][0];             // [q16][a32][ks8] = 4096 floats
#pragma unroll
  for (int r = 0; r < 4; ++r)
#pragma unroll
    for (int c = 0; c < 4; ++c)
      part[(((qg3 * 4 + r) * 32) + ag3 * 4 + c) * 8 + ks] = a3[r][c];
  __syncthreads();
  {
    const int idx = t * 2;
    const int q = idx >> 5, a = idx & 31;   // two consecutive a per thread
    const float invT = 1.0f / red[q][16];
    float o2[2];
#pragma unroll
    for (int o = 0; o < 2; ++o) {
      const float* p8 = part + ((size_t)(q * 32 + a + o)) * 8;
      float s = 0.f;
#pragma unroll
      for (int i = 0; i < 8; ++i) s += p8[i];
      s *= invT;
      const float p = pl_p[a + o];
      const float mean = log1pf(s);         // log(sum sm * v^p), robust near 1
      const float en = expf(mean / p);      // robust as p -> 0
      o2[o] = (en - BCONST) * pl_rg[a + o] / ONE_MINUS_B + pl_mn[a + o];
    }
    *(float2*)(ew + ((size_t)(b * 512 + q0g + q)) * 256 + h * 32 + a) =
        make_float2(o2[0], o2[1]);
  }
}

// ---------------------------------------------------------------------------
extern "C" void kernel_launch(void* const* d_in, const int* in_sizes, int n_in,
                              void* d_out, int out_size, void* d_ws, size_t ws_size,
                              hipStream_t stream) {
  const float* ctx  = (const float*)d_in[0];
  const float* WQ   = (const float*)d_in[1];
  const float* WKV  = (const float*)d_in[2];
  const float* WOUT = (const float*)d_in[3];
  const float* PP   = (const float*)d_in[4];
  float* ws    = (float*)d_ws;
  float* qkv   = ws + OFF_QKV;
  float* ew    = ws + OFF_EW;
  float* pminP = ws + OFF_PMIN;
  float* pmaxP = ws + OFF_PMAX;
  float* out   = (float*)d_out;

  // Fused Q|K|V projection + V min/max partials: 1024x768x256, 32x64 tiles
  gemm_t<32, 64, 2, 4, true><<<dim3(32, 12), 256, 0, stream>>>(
      ctx, WQ, WKV, 256, qkv, 768, 256, 256, pminP, pmaxP);
  // Fused attention (vpk folded in) + power-mean epilogue
  attn_k<<<dim3(16, 32), 256, 0, stream>>>(qkv, pminP, pmaxP, PP, ew);
  // Output projection: 1024x256x256, 32x32 tiles
  gemm_t<32, 32, 2, 2, false><<<dim3(32, 8), 256, 0, stream>>>(
      ew, WOUT, WOUT, 1 << 30, out, 256, 256, 256, nullptr, nullptr);
}